// Round 7
// baseline (262.833 us; speedup 1.0000x reference)
//
#include <hip/hip_runtime.h>
#include <hip/hip_cooperative_groups.h>

namespace cg = cooperative_groups;

#define C_    64
#define H_    40
#define W_    40
#define KS    11
#define HP    30          // H_ - KS + 1
#define NB    4
#define NL    900         // HP*HP
#define ND    59          // 2*(HP-1)+1
#define EPSF  1e-4f
#define PCH   6           // output rows per box job
#define SCW   65          // scratch row stride (odd -> conflict-free)
#define NINF  -3.4e38f
#define MPAD  1664        // 13*128 padded M=N
#define GSTEP 66600       // 40*MPAD + 40
#define NBLK  512         // cooperative grid (2 blocks/CU x 256 CU)
#define NGRAMJ 676        // 13*13*NB raw gram job space (band-filtered inside)
#define NBOXJ  700        // 175*NB compact box jobs
#define NPACKT 13312      // 2*NB*1664 pack tasks
#define SHB   34816       // shared bytes (gram tile is the max)

typedef _Float16 f16x8 __attribute__((ext_vector_type(8)));
typedef float    f32x4 __attribute__((ext_vector_type(4)));

// ---------------------------------------------------------------------------
// phase: pack one (img,b,pos) column into f16 octet layout; zero keys
// ---------------------------------------------------------------------------
__device__ __forceinline__
void ph_pack(int g, const float* __restrict__ im2, const float* __restrict__ im1,
             _Float16* __restrict__ packed, float* __restrict__ ssqbuf,
             unsigned int* __restrict__ keys) {
    if (g < NPACKT) {
        int pos = g % MPAD, q = g / MPAD, b = q & 3, img = q >> 2;
        const float* src = (img ? im1 : im2) + b * C_ * 1600;
        _Float16* dst = packed + ((size_t)img * NB + b) * (8 * MPAD * 8);
        float ss = 0.f;
        #pragma unroll
        for (int oct = 0; oct < 8; ++oct) {
            f16x8 h = {};
            if (pos < 1600) {
                #pragma unroll
                for (int j = 0; j < 8; ++j) {
                    float v = src[(oct * 8 + j) * 1600 + pos];
                    h[j] = (_Float16)v;
                    ss += v * v;
                }
            }
            *(f16x8*)&dst[(oct * MPAD + pos) * 8] = h;
        }
        if (img == 1 && pos < 1600) ssqbuf[b * 1600 + pos] = ss;
    } else if (g < NPACKT + NB * NL) {
        keys[g - NPACKT] = 0u;
    }
}

// ---------------------------------------------------------------------------
// phase: invnorm[b][ly][lx] via direct 11x11 sum of ssq
// ---------------------------------------------------------------------------
__device__ __forceinline__
void ph_norm(int g, const float* __restrict__ ssqbuf, float* __restrict__ invnorm) {
    if (g >= NB * NL) return;
    int b = g / NL, l = g - b * NL, ly = l / HP, lx = l - ly * HP;
    const float* p = ssqbuf + b * 1600 + ly * W_ + lx;
    float s = 0.f;
    for (int r = 0; r < KS; ++r) {
        #pragma unroll
        for (int sx = 0; sx < KS; ++sx) s += p[r * W_ + sx];
    }
    invnorm[g] = 1.f / fmaxf(sqrtf(s), EPSF);
}

// ---------------------------------------------------------------------------
// phase: one 128x128 gram tile (i,j) for batch b. Uses sh (34816 B).
// ---------------------------------------------------------------------------
__device__ __forceinline__
void ph_gram(int b, int i, int j, int tid, const _Float16* __restrict__ packed,
             _Float16* __restrict__ G, char* sh) {
    _Float16* smem = (_Float16*)sh;
    _Float16 (*As)[128][8] = (_Float16 (*)[128][8])smem;
    _Float16 (*Bs)[128][8] = (_Float16 (*)[128][8])(smem + 8192);
    const int w = tid >> 6, L = tid & 63, lq = L >> 4, lr = L & 15;

    const _Float16* pa = packed + (size_t)b * (8 * MPAD * 8);
    const _Float16* pb = packed + (size_t)(NB + b) * (8 * MPAD * 8);
    for (int t = tid; t < 1024; t += 256) {
        int oct = t >> 7, m = t & 127;
        *(f16x8*)&As[oct][m][0] = *(const f16x8*)&pa[(oct * MPAD + i * 128 + m) * 8];
        *(f16x8*)&Bs[oct][m][0] = *(const f16x8*)&pb[(oct * MPAD + j * 128 + m) * 8];
    }
    __syncthreads();

    const int mb = (w & 1) * 64, nb = (w >> 1) * 64;
    f16x8 a0[4], a1[4], b0[4], b1[4];
    #pragma unroll
    for (int q = 0; q < 4; ++q) {
        a0[q] = *(const f16x8*)&As[lq][mb + q * 16 + lr][0];
        a1[q] = *(const f16x8*)&As[4 + lq][mb + q * 16 + lr][0];
        b0[q] = *(const f16x8*)&Bs[lq][nb + q * 16 + lr][0];
        b1[q] = *(const f16x8*)&Bs[4 + lq][nb + q * 16 + lr][0];
    }
    f32x4 acc[4][4];
    #pragma unroll
    for (int mi = 0; mi < 4; ++mi)
        #pragma unroll
        for (int ni = 0; ni < 4; ++ni) {
            f32x4 c = {0.f, 0.f, 0.f, 0.f};
            c = __builtin_amdgcn_mfma_f32_16x16x32_f16(a0[mi], b0[ni], c, 0, 0, 0);
            c = __builtin_amdgcn_mfma_f32_16x16x32_f16(a1[mi], b1[ni], c, 0, 0, 0);
            acc[mi][ni] = c;
        }
    __syncthreads();   // frags in regs; overlay C on smem
    // C layout: row (A/m) = quad*4+reg, col (B/n) = lane&15
    #pragma unroll
    for (int mi = 0; mi < 4; ++mi)
        #pragma unroll
        for (int ni = 0; ni < 4; ++ni)
            #pragma unroll
            for (int rg = 0; rg < 4; ++rg)
                smem[(mb + mi * 16 + lq * 4 + rg) * 136 + nb + ni * 16 + lr] =
                    (_Float16)acc[mi][ni][rg];
    __syncthreads();
    _Float16* Gb = G + (size_t)b * (MPAD * MPAD);
    for (int t = tid; t < 2048; t += 256) {
        int row = t >> 4, seg = t & 15;
        *(f16x8*)&Gb[(size_t)(i * 128 + row) * MPAD + j * 128 + seg * 8] =
            *(const f16x8*)&smem[row * 136 + seg * 8];
    }
    __syncthreads();   // protect smem before a same-block follow-up job
}

// ---------------------------------------------------------------------------
// compact box-job decode: c in [0, NBOXJ) -> (b, dy, chunk)
// ---------------------------------------------------------------------------
__device__ __forceinline__
bool box_job(int c, int& b, int& dyv, int& chunk) {
    if (c >= NBOXJ) return false;
    b = c / 175;
    int r = c - b * 175;
    for (int dy = -(HP - 1); dy <= HP - 1; ++dy) {
        int ady = dy < 0 ? -dy : dy;
        int n = (HP - ady + PCH - 1) / PCH;
        if (r < n) { dyv = dy; chunk = r; return true; }
        r -= n;
    }
    return false;
}

// ---------------------------------------------------------------------------
// phase: one box job (b, dy, chunk): register sliding column sums over G
// planes + diagonal 11-tap sums + max over dx -> monotone-key atomics.
// ---------------------------------------------------------------------------
__device__ __forceinline__
void ph_box(int b, int dy, int chunk, int tid, const _Float16* __restrict__ G,
            const float* __restrict__ invnorm, unsigned int* __restrict__ keys,
            char* sh) {
    float* csum     = (float*)sh;              // 1600 f
    float* scratch  = (float*)(sh + 6400);     // 30*65 f
    float* partials = (float*)(sh + 14208);    // 120 f
    float* sInv     = (float*)(sh + 14688);    // PCH*HP f

    const int ady = dy < 0 ? -dy : dy;
    const int rows = HP - ady;
    const int pyLo = dy < 0 ? -dy : 0;
    const int py0 = pyLo + chunk * PCH;
    const int P = min(PCH, rows - chunk * PCH);

    __syncthreads();   // protect shared reuse across same-block jobs

    if (tid < P * HP) {
        int i = tid / HP, lx = tid - i * HP;
        sInv[i * HP + lx] = invnorm[b * NL + (py0 + i + dy) * HP + lx];
    }

    const _Float16* Gb = G + (size_t)b * (MPAD * MPAD);
    float s[8];
    f16x8 qa, qs;
    const _Float16* base = nullptr;
    if (tid < 200) {
        int e = tid * 8, x2 = e / 40, x1 = e - x2 * 40;
        base = Gb + (size_t)py0 * GSTEP + x2 * MPAD + dy * 40 + x1;
        #pragma unroll
        for (int j = 0; j < 8; ++j) s[j] = 0.f;
        for (int r = 0; r < KS; ++r) {
            f16x8 q = *(const f16x8*)(base + r * GSTEP);
            #pragma unroll
            for (int j = 0; j < 8; ++j) s[j] += (float)q[j];
        }
    }

    for (int i = 0; i < P; ++i) {
        const int py = py0 + i;
        if (tid < 200) {
            if (i > 0) {
                #pragma unroll
                for (int j = 0; j < 8; ++j) s[j] += (float)qa[j] - (float)qs[j];
            }
            float4* c4 = (float4*)(csum + tid * 8);
            c4[0] = make_float4(s[0], s[1], s[2], s[3]);
            c4[1] = make_float4(s[4], s[5], s[6], s[7]);
            if (i + 1 < P) {   // prefetch slide pair for iteration i+1
                qa = *(const f16x8*)(base + (i + 11) * GSTEP);
                qs = *(const f16x8*)(base + i * GSTEP);
            }
        }
        __syncthreads();                                   // A
        for (int t = tid; t < 5 * ND; t += 256) {
            int pg = t / ND, dxI = t - ND * pg;
            int dx = dxI - (HP - 1), pxb = 6 * pg;
            #pragma unroll
            for (int u = 0; u < 6; ++u) scratch[(pxb + u) * SCW + dxI] = NINF;
            int u0 = max(0, -dx - pxb), u1 = min(5, (HP - 1) - dx - pxb);
            if (u0 <= u1) {
                const float* cp = csum + dx;
                float run = 0.f;
                #pragma unroll
                for (int sr = 0; sr < KS; ++sr) run += cp[(pxb + u0 + sr) * (W_ + 1)];
                int u = u0;
                for (;;) {
                    scratch[(pxb + u) * SCW + dxI] = run * sInv[i * HP + pxb + u + dx];
                    if (++u > u1) break;
                    run += cp[(pxb + u + 10) * (W_ + 1)] - cp[(pxb + u - 1) * (W_ + 1)];
                }
            }
        }
        __syncthreads();                                   // B
        if (tid < 120) {
            int px = tid >> 2, q = tid & 3;
            float m = NINF;
            int d0 = q * 15, d1 = min(d0 + 15, ND);
            for (int d = d0; d < d1; ++d) m = fmaxf(m, scratch[px * SCW + d]);
            partials[tid] = m;
        }
        __syncthreads();                                   // C
        if (tid < HP) {
            float m = fmaxf(fmaxf(partials[tid * 4], partials[tid * 4 + 1]),
                            fmaxf(partials[tid * 4 + 2], partials[tid * 4 + 3]));
            unsigned int ub = __float_as_uint(m);
            unsigned int k = (ub & 0x80000000u) ? ~ub : (ub | 0x80000000u);
            atomicMax(&keys[b * NL + py * HP + tid], k);
        }
    }
}

__device__ __forceinline__
void ph_decode(int g, float* __restrict__ out) {
    if (g < NB * NL) {
        unsigned int k = ((unsigned int*)out)[g];
        unsigned int u = (k & 0x80000000u) ? (k ^ 0x80000000u) : ~k;
        out[g] = __uint_as_float(u);
    }
}

// ===========================================================================
// Cooperative single-dispatch kernel: pack -> (gram + norm) -> box -> decode
// ===========================================================================
__global__ __launch_bounds__(256, 2)
void k_all(const float* __restrict__ im1, const float* __restrict__ im2,
           _Float16* __restrict__ packed, float* __restrict__ ssqbuf,
           float* __restrict__ invnorm, _Float16* __restrict__ G,
           float* __restrict__ out) {
    __shared__ __align__(16) char sh[SHB];
    cg::grid_group grid = cg::this_grid();
    const int B = blockIdx.x, tid = threadIdx.x;
    const int g = B * 256 + tid;
    unsigned int* keys = (unsigned int*)out;

    ph_pack(g, im2, im1, packed, ssqbuf, keys);
    grid.sync();

    for (int jj = B; jj < NGRAMJ; jj += NBLK) {
        int b = jj / 169, t = jj - b * 169, ti = t / 13, tj = t - ti * 13;
        int dd = ti - tj; if (dd < 0) dd = -dd;
        if (dd <= 10) ph_gram(b, ti, tj, tid, packed, G, sh);
    }
    ph_norm(g, ssqbuf, invnorm);
    grid.sync();

    for (int cc = B; cc < NBOXJ; cc += NBLK) {
        int b, dyv, chunk;
        if (box_job(cc, b, dyv, chunk))
            ph_box(b, dyv, chunk, tid, G, invnorm, keys, sh);
    }
    grid.sync();

    ph_decode(g, out);
}

// ===========================================================================
// Fallback wrappers (5 dispatches, same phase bodies) if coop launch fails
// ===========================================================================
__global__ __launch_bounds__(256)
void k_pack_w(const float* im1, const float* im2, _Float16* packed,
              float* ssqbuf, float* out) {
    ph_pack(blockIdx.x * 256 + threadIdx.x, im2, im1, packed, ssqbuf,
            (unsigned int*)out);
}
__global__ __launch_bounds__(256)
void k_norm_w(const float* ssqbuf, float* invnorm) {
    ph_norm(blockIdx.x * 256 + threadIdx.x, ssqbuf, invnorm);
}
__global__ __launch_bounds__(256)
void k_gram_w(const _Float16* packed, _Float16* G) {
    __shared__ __align__(16) char sh[SHB];
    int jj = blockIdx.x;
    int b = jj / 169, t = jj - b * 169, ti = t / 13, tj = t - ti * 13;
    int dd = ti - tj; if (dd < 0) dd = -dd;
    if (dd <= 10) ph_gram(b, ti, tj, threadIdx.x, packed, G, sh);
}
__global__ __launch_bounds__(256)
void k_box_w(const _Float16* G, const float* invnorm, float* out) {
    __shared__ __align__(16) char sh[SHB];
    int b, dyv, chunk;
    if (box_job(blockIdx.x, b, dyv, chunk))
        ph_box(b, dyv, chunk, threadIdx.x, G, invnorm, (unsigned int*)out, sh);
}
__global__ __launch_bounds__(256)
void k_decode_w(float* out) {
    ph_decode(blockIdx.x * 256 + threadIdx.x, out);
}

extern "C" void kernel_launch(void* const* d_in, const int* in_sizes, int n_in,
                              void* d_out, int out_size, void* d_ws, size_t ws_size,
                              hipStream_t stream) {
    const float* im1 = (const float*)d_in[0];
    const float* im2 = (const float*)d_in[1];
    float* out = (float*)d_out;
    float* ssqbuf  = (float*)d_ws;                            // 25600 B
    float* invnorm = (float*)((char*)d_ws + 25600);           // 14400 B
    _Float16* packed = (_Float16*)((char*)d_ws + 65536);      // 1,703,936 B
    _Float16* G = (_Float16*)((char*)d_ws + 65536 + 1703936); // 22,151,168 B

    void* kargs[] = { (void*)&im1, (void*)&im2, (void*)&packed, (void*)&ssqbuf,
                      (void*)&invnorm, (void*)&G, (void*)&out };
    hipError_t err = hipLaunchCooperativeKernel((const void*)k_all, dim3(NBLK),
                                                dim3(256), kargs, 0, stream);
    if (err != hipSuccess) {
        (void)hipGetLastError();   // clear sticky error, use fallback path
        k_pack_w<<<(NPACKT + NB * NL + 255) / 256, 256, 0, stream>>>(
            im1, im2, packed, ssqbuf, out);
        k_norm_w<<<(NB * NL + 255) / 256, 256, 0, stream>>>(ssqbuf, invnorm);
        k_gram_w<<<NGRAMJ, 256, 0, stream>>>(packed, G);
        k_box_w<<<NBOXJ, 256, 0, stream>>>(G, invnorm, out);
        k_decode_w<<<(NB * NL + 255) / 256, 256, 0, stream>>>(out);
    }
}

// Round 8
// 171.195 us; speedup vs baseline: 1.5353x; 1.5353x over previous
//
#include <hip/hip_runtime.h>

#define C_    64
#define H_    40
#define W_    40
#define KS    11
#define HP    30          // H_ - KS + 1
#define NB    4
#define NL    900         // HP*HP
#define ND    59          // 2*(HP-1)+1
#define EPSF  1e-4f
#define PCH   6           // output rows per box job
#define SCW   65          // scratch row stride (odd -> conflict-free)
#define NINF  -3.4e38f
#define MPAD  1664        // 13*128 padded M=N
#define GSTEP 66600       // 40*MPAD + 40: plane-to-plane step along the dy diagonal
#define NBOXJ 700         // 175*NB box jobs (exact cover)
#define SHB   34816       // 128*136*2 bytes: gram tile / norm overlay

typedef _Float16 f16x8 __attribute__((ext_vector_type(8)));
typedef float    f32x4 __attribute__((ext_vector_type(4)));

// ===========================================================================
// k_A: blocks 0..675 = gram tiles (direct fp32 load, f16 convert in staging);
//      blocks 676..679 = per-batch invnorm + zero keys (+counter).
// G[b][m][n] = sum_c im2[c][m] * im1[c][n], f16, stride MPAD.
// ===========================================================================
__global__ __launch_bounds__(256, 2)
void k_A(const float* __restrict__ im1, const float* __restrict__ im2,
         _Float16* __restrict__ G, float* __restrict__ invnorm,
         unsigned int* __restrict__ keys, unsigned int* __restrict__ counter) {
    __shared__ __align__(16) char sh[SHB];
    const int B = blockIdx.x, tid = threadIdx.x;

    if (B >= 676) {                       // ---- norm + init block ----
        const int b = B - 676;
        float* ssq = (float*)sh;          // 1600 f
        float* colsum = ssq + 1600;       // 1200 f
        const float* imb = im1 + b * C_ * 1600;
        for (int i = tid; i < 1600; i += 256) {
            float s = 0.f;
            #pragma unroll 8
            for (int c = 0; c < C_; ++c) { float v = imb[c * 1600 + i]; s += v * v; }
            ssq[i] = s;
        }
        __syncthreads();
        for (int t = tid; t < HP * W_; t += 256) {
            int yy = t / W_, x = t - yy * W_;
            float s = 0.f;
            #pragma unroll
            for (int r = 0; r < KS; ++r) s += ssq[(yy + r) * W_ + x];
            colsum[t] = s;
        }
        __syncthreads();
        for (int t = tid; t < NL; t += 256) {
            int ly = t / HP, lx = t - ly * HP;
            float s = 0.f;
            #pragma unroll
            for (int sx = 0; sx < KS; ++sx) s += colsum[ly * W_ + lx + sx];
            invnorm[b * NL + t] = 1.f / fmaxf(sqrtf(s), EPSF);
        }
        for (int t = tid; t < NL; t += 256) keys[b * NL + t] = 0u;
        if (b == 0 && tid == 0) *counter = 0u;
        return;
    }

    // ---- gram tile ----
    const int b = B / 169, t0 = B - b * 169, i = t0 / 13, j = t0 - i * 13;
    int dd = i - j; if (dd < 0) dd = -dd;
    if (dd > 10) return;                  // outside the |dy|<=29 band

    _Float16* smem = (_Float16*)sh;
    _Float16 (*As)[128][8] = (_Float16 (*)[128][8])smem;
    _Float16 (*Bs)[128][8] = (_Float16 (*)[128][8])(smem + 8192);
    const int w = tid >> 6, L = tid & 63, lq = L >> 4, lr = L & 15;

    const float* p2 = im2 + b * C_ * 1600;   // A = im2 (rows/M)
    const float* p1 = im1 + b * C_ * 1600;   // B = im1 (cols/N)
    for (int t = tid; t < 1024; t += 256) {
        int oct = t >> 7, m = t & 127;
        int posA = i * 128 + m, posB = j * 128 + m;
        f16x8 ha = {}, hb = {};
        if (posA < 1600) {
            const float* pa = p2 + oct * 8 * 1600 + posA;
            #pragma unroll
            for (int k = 0; k < 8; ++k) ha[k] = (_Float16)pa[k * 1600];
        }
        if (posB < 1600) {
            const float* pb = p1 + oct * 8 * 1600 + posB;
            #pragma unroll
            for (int k = 0; k < 8; ++k) hb[k] = (_Float16)pb[k * 1600];
        }
        *(f16x8*)&As[oct][m][0] = ha;
        *(f16x8*)&Bs[oct][m][0] = hb;
    }
    __syncthreads();

    const int mb = (w & 1) * 64, nb = (w >> 1) * 64;
    f16x8 a0[4], a1[4], b0[4], b1[4];
    #pragma unroll
    for (int q = 0; q < 4; ++q) {
        a0[q] = *(const f16x8*)&As[lq][mb + q * 16 + lr][0];
        a1[q] = *(const f16x8*)&As[4 + lq][mb + q * 16 + lr][0];
        b0[q] = *(const f16x8*)&Bs[lq][nb + q * 16 + lr][0];
        b1[q] = *(const f16x8*)&Bs[4 + lq][nb + q * 16 + lr][0];
    }
    f32x4 acc[4][4];
    #pragma unroll
    for (int mi = 0; mi < 4; ++mi)
        #pragma unroll
        for (int ni = 0; ni < 4; ++ni) {
            f32x4 c = {0.f, 0.f, 0.f, 0.f};
            c = __builtin_amdgcn_mfma_f32_16x16x32_f16(a0[mi], b0[ni], c, 0, 0, 0);
            c = __builtin_amdgcn_mfma_f32_16x16x32_f16(a1[mi], b1[ni], c, 0, 0, 0);
            acc[mi][ni] = c;
        }
    __syncthreads();   // frags in regs; overlay C on smem
    // C layout: row (A/m) = quad*4+reg, col (B/n) = lane&15  [verified R3-R6]
    #pragma unroll
    for (int mi = 0; mi < 4; ++mi)
        #pragma unroll
        for (int ni = 0; ni < 4; ++ni)
            #pragma unroll
            for (int rg = 0; rg < 4; ++rg)
                smem[(mb + mi * 16 + lq * 4 + rg) * 136 + nb + ni * 16 + lr] =
                    (_Float16)acc[mi][ni][rg];
    __syncthreads();
    _Float16* Gb = G + (size_t)b * (MPAD * MPAD);
    for (int t = tid; t < 2048; t += 256) {
        int row = t >> 4, seg = t & 15;
        *(f16x8*)&Gb[(size_t)(i * 128 + row) * MPAD + j * 128 + seg * 8] =
            *(const f16x8*)&smem[row * 136 + seg * 8];
    }
}

// ===========================================================================
// k_B: one box job per block (register sliding column sums over G planes +
// diagonal 11-tap sums + max over dx -> monotone-key atomics); the last
// block to finish decodes keys -> float in place.
// ===========================================================================
__global__ __launch_bounds__(256, 4)
void k_B(const _Float16* __restrict__ G, const float* __restrict__ invnorm,
         float* __restrict__ out, unsigned int* __restrict__ counter) {
    __shared__ float csum[1600];
    __shared__ float scratch[HP * SCW];
    __shared__ float partials[120];
    __shared__ float sInv[PCH * HP];
    __shared__ unsigned int islast;
    unsigned int* keys = (unsigned int*)out;
    const int tid = threadIdx.x;

    // decode job id -> (b, dy, chunk); exact cover, always valid
    int c = blockIdx.x;
    int b = c / 175, r = c - b * 175, dy = 0, chunk = 0;
    for (int d = -(HP - 1); d <= HP - 1; ++d) {
        int ady = d < 0 ? -d : d;
        int n = (HP - ady + PCH - 1) / PCH;
        if (r < n) { dy = d; chunk = r; break; }
        r -= n;
    }
    const int ady = dy < 0 ? -dy : dy;
    const int rows = HP - ady;
    const int pyLo = dy < 0 ? -dy : 0;
    const int py0 = pyLo + chunk * PCH;
    const int P = min(PCH, rows - chunk * PCH);

    if (tid < P * HP) {
        int i = tid / HP, lx = tid - i * HP;
        sInv[i * HP + lx] = invnorm[b * NL + (py0 + i + dy) * HP + lx];
    }

    const _Float16* Gb = G + (size_t)b * (MPAD * MPAD);
    float s[8];
    f16x8 qa, qs;
    const _Float16* base = nullptr;
    if (tid < 200) {
        int e = tid * 8, x2 = e / 40, x1 = e - x2 * 40;
        base = Gb + (size_t)py0 * GSTEP + x2 * MPAD + dy * 40 + x1;
        #pragma unroll
        for (int j = 0; j < 8; ++j) s[j] = 0.f;
        for (int rr = 0; rr < KS; ++rr) {
            f16x8 q = *(const f16x8*)(base + rr * GSTEP);
            #pragma unroll
            for (int j = 0; j < 8; ++j) s[j] += (float)q[j];
        }
    }

    for (int i = 0; i < P; ++i) {
        const int py = py0 + i;
        if (tid < 200) {
            if (i > 0) {
                #pragma unroll
                for (int j = 0; j < 8; ++j) s[j] += (float)qa[j] - (float)qs[j];
            }
            float4* c4 = (float4*)(csum + tid * 8);
            c4[0] = make_float4(s[0], s[1], s[2], s[3]);
            c4[1] = make_float4(s[4], s[5], s[6], s[7]);
            if (i + 1 < P) {   // prefetch slide pair for iteration i+1
                qa = *(const f16x8*)(base + (i + 11) * GSTEP);
                qs = *(const f16x8*)(base + i * GSTEP);
            }
        }
        __syncthreads();                                   // A
        for (int t = tid; t < 5 * ND; t += 256) {
            int pg = t / ND, dxI = t - ND * pg;
            int dx = dxI - (HP - 1), pxb = 6 * pg;
            #pragma unroll
            for (int u = 0; u < 6; ++u) scratch[(pxb + u) * SCW + dxI] = NINF;
            int u0 = max(0, -dx - pxb), u1 = min(5, (HP - 1) - dx - pxb);
            if (u0 <= u1) {
                const float* cp = csum + dx;
                float run = 0.f;
                #pragma unroll
                for (int sr = 0; sr < KS; ++sr) run += cp[(pxb + u0 + sr) * (W_ + 1)];
                int u = u0;
                for (;;) {
                    scratch[(pxb + u) * SCW + dxI] = run * sInv[i * HP + pxb + u + dx];
                    if (++u > u1) break;
                    run += cp[(pxb + u + 10) * (W_ + 1)] - cp[(pxb + u - 1) * (W_ + 1)];
                }
            }
        }
        __syncthreads();                                   // B
        if (tid < 120) {
            int px = tid >> 2, q = tid & 3;
            float m = NINF;
            int d0 = q * 15, d1 = min(d0 + 15, ND);
            for (int d = d0; d < d1; ++d) m = fmaxf(m, scratch[px * SCW + d]);
            partials[tid] = m;
        }
        __syncthreads();                                   // C
        if (tid < HP) {
            float m = fmaxf(fmaxf(partials[tid * 4], partials[tid * 4 + 1]),
                            fmaxf(partials[tid * 4 + 2], partials[tid * 4 + 3]));
            unsigned int ub = __float_as_uint(m);
            unsigned int k = (ub & 0x80000000u) ? ~ub : (ub | 0x80000000u);
            atomicMax(&keys[b * NL + py * HP + tid], k);
        }
        __syncthreads();                                   // D (protect csum rewrite)
    }

    // ---- last-block in-place decode ----
    __threadfence();
    if (tid == 0) islast = (atomicAdd(counter, 1u) == NBOXJ - 1) ? 1u : 0u;
    __syncthreads();
    if (islast) {
        for (int i = tid; i < NB * NL; i += 256) {
            unsigned int k = atomicOr(&keys[i], 0u);   // coherent read
            unsigned int u = (k & 0x80000000u) ? (k ^ 0x80000000u) : ~k;
            out[i] = __uint_as_float(u);
        }
    }
}

extern "C" void kernel_launch(void* const* d_in, const int* in_sizes, int n_in,
                              void* d_out, int out_size, void* d_ws, size_t ws_size,
                              hipStream_t stream) {
    const float* im1 = (const float*)d_in[0];
    const float* im2 = (const float*)d_in[1];
    float* out = (float*)d_out;
    unsigned int* counter = (unsigned int*)d_ws;               // 4 B
    float* invnorm = (float*)((char*)d_ws + 64);               // 14400 B
    _Float16* G = (_Float16*)((char*)d_ws + 65536);            // 22,151,168 B

    k_A<<<680, 256, 0, stream>>>(im1, im2, G, invnorm, (unsigned int*)out, counter);
    k_B<<<NBOXJ, 256, 0, stream>>>(G, invnorm, out, counter);
}

// Round 9
// 111.359 us; speedup vs baseline: 2.3602x; 1.5373x over previous
//
#include <hip/hip_runtime.h>

#define C_    64
#define H_    40
#define W_    40
#define KS    11
#define HP    30          // H_ - KS + 1
#define NB    4
#define NL    900         // HP*HP
#define ND    59          // 2*(HP-1)+1
#define EPSF  1e-4f
#define PCH   6           // output rows per box job
#define SCW   65          // scratch row stride (odd -> conflict-free)
#define NINF  -3.4e38f
#define MPAD  1664        // 13*128 padded M=N
#define GSTEP 66600       // 40*MPAD + 40: plane-to-plane step along the dy diagonal
#define NBOXJ 700         // 175*NB box jobs (exact cover)
#define SHB   34816       // 128*136*2 bytes: gram tile / norm overlay

typedef _Float16 f16x8 __attribute__((ext_vector_type(8)));
typedef float    f32x4 __attribute__((ext_vector_type(4)));

// ===========================================================================
// k_A: blocks 0..675 = gram tiles (direct fp32 load, f16 convert in staging);
//      blocks 676..679 = per-batch invnorm.
// G[b][m][n] = sum_c im2[c][m] * im1[c][n], f16, stride MPAD.
// ===========================================================================
__global__ __launch_bounds__(256, 2)
void k_A(const float* __restrict__ im1, const float* __restrict__ im2,
         _Float16* __restrict__ G, float* __restrict__ invnorm) {
    __shared__ __align__(16) char sh[SHB];
    const int B = blockIdx.x, tid = threadIdx.x;

    if (B >= 676) {                       // ---- norm block ----
        const int b = B - 676;
        float* ssq = (float*)sh;          // 1600 f
        float* colsum = ssq + 1600;       // 1200 f
        const float* imb = im1 + b * C_ * 1600;
        for (int i = tid; i < 1600; i += 256) {
            float s = 0.f;
            #pragma unroll 8
            for (int c = 0; c < C_; ++c) { float v = imb[c * 1600 + i]; s += v * v; }
            ssq[i] = s;
        }
        __syncthreads();
        for (int t = tid; t < HP * W_; t += 256) {
            int yy = t / W_, x = t - yy * W_;
            float s = 0.f;
            #pragma unroll
            for (int r = 0; r < KS; ++r) s += ssq[(yy + r) * W_ + x];
            colsum[t] = s;
        }
        __syncthreads();
        for (int t = tid; t < NL; t += 256) {
            int ly = t / HP, lx = t - ly * HP;
            float s = 0.f;
            #pragma unroll
            for (int sx = 0; sx < KS; ++sx) s += colsum[ly * W_ + lx + sx];
            invnorm[b * NL + t] = 1.f / fmaxf(sqrtf(s), EPSF);
        }
        return;
    }

    // ---- gram tile ----
    const int b = B / 169, t0 = B - b * 169, i = t0 / 13, j = t0 - i * 13;
    int dd = i - j; if (dd < 0) dd = -dd;
    if (dd > 10) return;                  // outside the |dy|<=29 band

    _Float16* smem = (_Float16*)sh;
    _Float16 (*As)[128][8] = (_Float16 (*)[128][8])smem;
    _Float16 (*Bs)[128][8] = (_Float16 (*)[128][8])(smem + 8192);
    const int w = tid >> 6, L = tid & 63, lq = L >> 4, lr = L & 15;

    const float* p2 = im2 + b * C_ * 1600;   // A = im2 (rows/M)
    const float* p1 = im1 + b * C_ * 1600;   // B = im1 (cols/N)
    for (int t = tid; t < 1024; t += 256) {
        int oct = t >> 7, m = t & 127;
        int posA = i * 128 + m, posB = j * 128 + m;
        f16x8 ha = {}, hb = {};
        if (posA < 1600) {
            const float* pa = p2 + oct * 8 * 1600 + posA;
            #pragma unroll
            for (int k = 0; k < 8; ++k) ha[k] = (_Float16)pa[k * 1600];
        }
        if (posB < 1600) {
            const float* pb = p1 + oct * 8 * 1600 + posB;
            #pragma unroll
            for (int k = 0; k < 8; ++k) hb[k] = (_Float16)pb[k * 1600];
        }
        *(f16x8*)&As[oct][m][0] = ha;
        *(f16x8*)&Bs[oct][m][0] = hb;
    }
    __syncthreads();

    const int mb = (w & 1) * 64, nb = (w >> 1) * 64;
    f16x8 a0[4], a1[4], b0[4], b1[4];
    #pragma unroll
    for (int q = 0; q < 4; ++q) {
        a0[q] = *(const f16x8*)&As[lq][mb + q * 16 + lr][0];
        a1[q] = *(const f16x8*)&As[4 + lq][mb + q * 16 + lr][0];
        b0[q] = *(const f16x8*)&Bs[lq][nb + q * 16 + lr][0];
        b1[q] = *(const f16x8*)&Bs[4 + lq][nb + q * 16 + lr][0];
    }
    f32x4 acc[4][4];
    #pragma unroll
    for (int mi = 0; mi < 4; ++mi)
        #pragma unroll
        for (int ni = 0; ni < 4; ++ni) {
            f32x4 c = {0.f, 0.f, 0.f, 0.f};
            c = __builtin_amdgcn_mfma_f32_16x16x32_f16(a0[mi], b0[ni], c, 0, 0, 0);
            c = __builtin_amdgcn_mfma_f32_16x16x32_f16(a1[mi], b1[ni], c, 0, 0, 0);
            acc[mi][ni] = c;
        }
    __syncthreads();   // frags in regs; overlay C on smem
    // C layout: row (A/m) = quad*4+reg, col (B/n) = lane&15  [verified R3-R8]
    #pragma unroll
    for (int mi = 0; mi < 4; ++mi)
        #pragma unroll
        for (int ni = 0; ni < 4; ++ni)
            #pragma unroll
            for (int rg = 0; rg < 4; ++rg)
                smem[(mb + mi * 16 + lq * 4 + rg) * 136 + nb + ni * 16 + lr] =
                    (_Float16)acc[mi][ni][rg];
    __syncthreads();
    _Float16* Gb = G + (size_t)b * (MPAD * MPAD);
    for (int t = tid; t < 2048; t += 256) {
        int row = t >> 4, seg = t & 15;
        *(f16x8*)&Gb[(size_t)(i * 128 + row) * MPAD + j * 128 + seg * 8] =
            *(const f16x8*)&smem[row * 136 + seg * 8];
    }
}

// ===========================================================================
// k_B: one box job per block. Register sliding column sums over G planes +
// diagonal 11-tap sums + max over dx. Result rows go to a PRIVATE slice of
// part[b][dyI][py][px] — plain coalesced stores, no atomics, no fences.
// ===========================================================================
__global__ __launch_bounds__(256, 4)
void k_B(const _Float16* __restrict__ G, const float* __restrict__ invnorm,
         float* __restrict__ part) {
    __shared__ float csum[1600];
    __shared__ float scratch[HP * SCW];
    __shared__ float partials[120];
    __shared__ float sInv[PCH * HP];
    const int tid = threadIdx.x;

    // decode job id -> (b, dy, chunk); exact cover
    int c = blockIdx.x;
    int b = c / 175, r = c - b * 175, dy = 0, chunk = 0;
    for (int d = -(HP - 1); d <= HP - 1; ++d) {
        int ady = d < 0 ? -d : d;
        int n = (HP - ady + PCH - 1) / PCH;
        if (r < n) { dy = d; chunk = r; break; }
        r -= n;
    }
    const int ady = dy < 0 ? -dy : dy;
    const int rows = HP - ady;
    const int pyLo = dy < 0 ? -dy : 0;
    const int py0 = pyLo + chunk * PCH;
    const int P = min(PCH, rows - chunk * PCH);
    const int dyI = dy + (HP - 1);

    if (tid < P * HP) {
        int i = tid / HP, lx = tid - i * HP;
        sInv[i * HP + lx] = invnorm[b * NL + (py0 + i + dy) * HP + lx];
    }

    const _Float16* Gb = G + (size_t)b * (MPAD * MPAD);
    float s[8];
    f16x8 qa, qs;
    const _Float16* base = nullptr;
    if (tid < 200) {
        int e = tid * 8, x2 = e / 40, x1 = e - x2 * 40;
        base = Gb + (size_t)py0 * GSTEP + x2 * MPAD + dy * 40 + x1;
        #pragma unroll
        for (int j = 0; j < 8; ++j) s[j] = 0.f;
        for (int rr = 0; rr < KS; ++rr) {
            f16x8 q = *(const f16x8*)(base + rr * GSTEP);
            #pragma unroll
            for (int j = 0; j < 8; ++j) s[j] += (float)q[j];
        }
    }

    for (int i = 0; i < P; ++i) {
        const int py = py0 + i;
        if (tid < 200) {
            if (i > 0) {
                #pragma unroll
                for (int j = 0; j < 8; ++j) s[j] += (float)qa[j] - (float)qs[j];
            }
            float4* c4 = (float4*)(csum + tid * 8);
            c4[0] = make_float4(s[0], s[1], s[2], s[3]);
            c4[1] = make_float4(s[4], s[5], s[6], s[7]);
            if (i + 1 < P) {   // prefetch slide pair for iteration i+1
                qa = *(const f16x8*)(base + (i + 11) * GSTEP);
                qs = *(const f16x8*)(base + i * GSTEP);
            }
        }
        __syncthreads();                                   // A
        for (int t = tid; t < 5 * ND; t += 256) {
            int pg = t / ND, dxI = t - ND * pg;
            int dx = dxI - (HP - 1), pxb = 6 * pg;
            #pragma unroll
            for (int u = 0; u < 6; ++u) scratch[(pxb + u) * SCW + dxI] = NINF;
            int u0 = max(0, -dx - pxb), u1 = min(5, (HP - 1) - dx - pxb);
            if (u0 <= u1) {
                const float* cp = csum + dx;
                float run = 0.f;
                #pragma unroll
                for (int sr = 0; sr < KS; ++sr) run += cp[(pxb + u0 + sr) * (W_ + 1)];
                int u = u0;
                for (;;) {
                    scratch[(pxb + u) * SCW + dxI] = run * sInv[i * HP + pxb + u + dx];
                    if (++u > u1) break;
                    run += cp[(pxb + u + 10) * (W_ + 1)] - cp[(pxb + u - 1) * (W_ + 1)];
                }
            }
        }
        __syncthreads();                                   // B
        if (tid < 120) {
            int px = tid >> 2, q = tid & 3;
            float m = NINF;
            int d0 = q * 15, d1 = min(d0 + 15, ND);
            for (int d = d0; d < d1; ++d) m = fmaxf(m, scratch[px * SCW + d]);
            partials[tid] = m;
        }
        __syncthreads();                                   // C
        if (tid < HP) {
            float m = fmaxf(fmaxf(partials[tid * 4], partials[tid * 4 + 1]),
                            fmaxf(partials[tid * 4 + 2], partials[tid * 4 + 3]));
            part[(((size_t)b * ND + dyI) * HP + py) * HP + tid] = m;
        }
        // no trailing sync: next iteration's sync A orders the shared rewrites
    }
}

// ===========================================================================
// k_C: out[b,py,px] = max over the 30 valid dys: dyI in [29-py, 58-py]
// ===========================================================================
__global__ __launch_bounds__(256)
void k_C(const float* __restrict__ part, float* __restrict__ out) {
    int g = blockIdx.x * 256 + threadIdx.x;
    if (g >= NB * NL) return;
    int b = g / NL, l = g - b * NL, py = l / HP, px = l - py * HP;
    const float* p = part + (((size_t)b * ND + (HP - 1 - py)) * HP + py) * HP + px;
    float m = NINF;
    #pragma unroll
    for (int j = 0; j < HP; ++j) m = fmaxf(m, p[(size_t)j * HP * HP]);
    out[g] = m;
}

extern "C" void kernel_launch(void* const* d_in, const int* in_sizes, int n_in,
                              void* d_out, int out_size, void* d_ws, size_t ws_size,
                              hipStream_t stream) {
    const float* im1 = (const float*)d_in[0];
    const float* im2 = (const float*)d_in[1];
    float* out = (float*)d_out;
    float* invnorm = (float*)((char*)d_ws + 64);               // 14,400 B
    float* part = (float*)((char*)d_ws + 16384);               // 849,600 B
    _Float16* G = (_Float16*)((char*)d_ws + 1048576);          // 22,151,168 B

    k_A<<<680, 256, 0, stream>>>(im1, im2, G, invnorm);
    k_B<<<NBOXJ, 256, 0, stream>>>(G, invnorm, part);
    k_C<<<(NB * NL + 255) / 256, 256, 0, stream>>>(part, out);
}

// Round 10
// 106.574 us; speedup vs baseline: 2.4662x; 1.0449x over previous
//
#include <hip/hip_runtime.h>

#define C_    64
#define H_    40
#define W_    40
#define KS    11
#define HP    30          // H_ - KS + 1
#define NB    4
#define NL    900         // HP*HP
#define ND    59          // 2*(HP-1)+1
#define EPSF  1e-4f
#define PCH   6           // output rows per box job
#define SCW   65          // scratch row stride (odd -> conflict-free)
#define NINF  -3.4e38f
#define NBOXJ 700         // 175*NB box jobs (exact cover)
#define SHB   34816       // 128*136*2 bytes: gram tile / norm overlay
#define TILEB 1600        // elements per 40x40 G tile

typedef _Float16 f16x8 __attribute__((ext_vector_type(8)));
typedef float    f32x4 __attribute__((ext_vector_type(4)));

// ===========================================================================
// k_A: blocks 0..675 = gram tiles -> G in 40x40-tile layout
//      Gt[b][mr][nc][r40][c40], tile idx = mr*40+nc, each tile 3200 B.
//      blocks 676..679 = per-batch invnorm.
// ===========================================================================
__global__ __launch_bounds__(256, 2)
void k_A(const float* __restrict__ im1, const float* __restrict__ im2,
         _Float16* __restrict__ G, float* __restrict__ invnorm) {
    __shared__ __align__(16) char sh[SHB];
    const int B = blockIdx.x, tid = threadIdx.x;

    if (B >= 676) {                       // ---- norm block ----
        const int b = B - 676;
        float* ssq = (float*)sh;          // 1600 f
        float* colsum = ssq + 1600;       // 1200 f
        const float* imb = im1 + b * C_ * 1600;
        for (int i = tid; i < 1600; i += 256) {
            float s = 0.f;
            #pragma unroll 8
            for (int c = 0; c < C_; ++c) { float v = imb[c * 1600 + i]; s += v * v; }
            ssq[i] = s;
        }
        __syncthreads();
        for (int t = tid; t < HP * W_; t += 256) {
            int yy = t / W_, x = t - yy * W_;
            float s = 0.f;
            #pragma unroll
            for (int r = 0; r < KS; ++r) s += ssq[(yy + r) * W_ + x];
            colsum[t] = s;
        }
        __syncthreads();
        for (int t = tid; t < NL; t += 256) {
            int ly = t / HP, lx = t - ly * HP;
            float s = 0.f;
            #pragma unroll
            for (int sx = 0; sx < KS; ++sx) s += colsum[ly * W_ + lx + sx];
            invnorm[b * NL + t] = 1.f / fmaxf(sqrtf(s), EPSF);
        }
        return;
    }

    // ---- gram tile ----
    const int b = B / 169, t0 = B - b * 169, i = t0 / 13, j = t0 - i * 13;
    int dd = i - j; if (dd < 0) dd = -dd;
    if (dd > 10) return;                  // outside the |m-n|<=1199 band

    _Float16* smem = (_Float16*)sh;
    _Float16 (*As)[128][8] = (_Float16 (*)[128][8])smem;
    _Float16 (*Bs)[128][8] = (_Float16 (*)[128][8])(smem + 8192);
    const int w = tid >> 6, L = tid & 63, lq = L >> 4, lr = L & 15;

    const float* p2 = im2 + b * C_ * 1600;   // A = im2 (rows/M)
    const float* p1 = im1 + b * C_ * 1600;   // B = im1 (cols/N)
    for (int t = tid; t < 1024; t += 256) {
        int oct = t >> 7, m = t & 127;
        int posA = i * 128 + m, posB = j * 128 + m;
        f16x8 ha = {}, hb = {};
        if (posA < 1600) {
            const float* pa = p2 + oct * 8 * 1600 + posA;
            #pragma unroll
            for (int k = 0; k < 8; ++k) ha[k] = (_Float16)pa[k * 1600];
        }
        if (posB < 1600) {
            const float* pb = p1 + oct * 8 * 1600 + posB;
            #pragma unroll
            for (int k = 0; k < 8; ++k) hb[k] = (_Float16)pb[k * 1600];
        }
        *(f16x8*)&As[oct][m][0] = ha;
        *(f16x8*)&Bs[oct][m][0] = hb;
    }
    __syncthreads();

    const int mb = (w & 1) * 64, nb = (w >> 1) * 64;
    f16x8 a0[4], a1[4], b0[4], b1[4];
    #pragma unroll
    for (int q = 0; q < 4; ++q) {
        a0[q] = *(const f16x8*)&As[lq][mb + q * 16 + lr][0];
        a1[q] = *(const f16x8*)&As[4 + lq][mb + q * 16 + lr][0];
        b0[q] = *(const f16x8*)&Bs[lq][nb + q * 16 + lr][0];
        b1[q] = *(const f16x8*)&Bs[4 + lq][nb + q * 16 + lr][0];
    }
    f32x4 acc[4][4];
    #pragma unroll
    for (int mi = 0; mi < 4; ++mi)
        #pragma unroll
        for (int ni = 0; ni < 4; ++ni) {
            f32x4 c = {0.f, 0.f, 0.f, 0.f};
            c = __builtin_amdgcn_mfma_f32_16x16x32_f16(a0[mi], b0[ni], c, 0, 0, 0);
            c = __builtin_amdgcn_mfma_f32_16x16x32_f16(a1[mi], b1[ni], c, 0, 0, 0);
            acc[mi][ni] = c;
        }
    __syncthreads();   // frags in regs; overlay C on smem
    // C layout: row (A/m) = quad*4+reg, col (B/n) = lane&15  [verified R3-R9]
    #pragma unroll
    for (int mi = 0; mi < 4; ++mi)
        #pragma unroll
        for (int ni = 0; ni < 4; ++ni)
            #pragma unroll
            for (int rg = 0; rg < 4; ++rg)
                smem[(mb + mi * 16 + lq * 4 + rg) * 136 + nb + ni * 16 + lr] =
                    (_Float16)acc[mi][ni][rg];
    __syncthreads();
    // scatter into tile layout; each 8-col segment lies in exactly one tile
    _Float16* Gb = G + (size_t)b * (1600 * TILEB);
    for (int t = tid; t < 2048; t += 256) {
        int row = t >> 4, seg = t & 15;
        int m = i * 128 + row, n = j * 128 + seg * 8;
        if (m < 1600 && n < 1600) {
            int mr = m / 40, r40 = m - mr * 40;
            int nc = n / 40, c40 = n - nc * 40;
            *(f16x8*)&Gb[(size_t)(mr * 40 + nc) * TILEB + r40 * 40 + c40] =
                *(const f16x8*)&smem[row * 136 + seg * 8];
        }
    }
}

// ===========================================================================
// k_B: one box job per block. Plane (y,dy) = contiguous tile y*41+dy (3.2 KB,
// fully coalesced). Register sliding column sums + diagonal 11-tap sums +
// max over dx -> private slice of part[b][dyI][py][px], plain stores.
// ===========================================================================
__global__ __launch_bounds__(256, 4)
void k_B(const _Float16* __restrict__ G, const float* __restrict__ invnorm,
         float* __restrict__ part) {
    __shared__ float csum[1600];
    __shared__ float scratch[HP * SCW];
    __shared__ float partials[120];
    __shared__ float sInv[PCH * HP];
    const int tid = threadIdx.x;

    // decode job id -> (b, dy, chunk); exact cover
    int c = blockIdx.x;
    int b = c / 175, r = c - b * 175, dy = 0, chunk = 0;
    for (int d = -(HP - 1); d <= HP - 1; ++d) {
        int ady = d < 0 ? -d : d;
        int n = (HP - ady + PCH - 1) / PCH;
        if (r < n) { dy = d; chunk = r; break; }
        r -= n;
    }
    const int ady = dy < 0 ? -dy : dy;
    const int rows = HP - ady;
    const int pyLo = dy < 0 ? -dy : 0;
    const int py0 = pyLo + chunk * PCH;
    const int P = min(PCH, rows - chunk * PCH);
    const int dyI = dy + (HP - 1);

    if (tid < P * HP) {
        int i = tid / HP, lx = tid - i * HP;
        sInv[i * HP + lx] = invnorm[b * NL + (py0 + i + dy) * HP + lx];
    }

    // plane p lives at tile (py0+p)*41 + dy; lane offset = tid*8 (e<1600)
    const _Float16* base = G + ((size_t)b * 1600 + (size_t)(py0 * 41 + dy)) * TILEB
                             + tid * 8;
    const size_t PSTEP = (size_t)41 * TILEB;    // plane-to-plane stride
    float s[8];
    f16x8 qa, qs;
    if (tid < 200) {
        #pragma unroll
        for (int j = 0; j < 8; ++j) s[j] = 0.f;
        for (int rr = 0; rr < KS; ++rr) {
            f16x8 q = *(const f16x8*)(base + rr * PSTEP);
            #pragma unroll
            for (int j = 0; j < 8; ++j) s[j] += (float)q[j];
        }
    }

    for (int i = 0; i < P; ++i) {
        const int py = py0 + i;
        if (tid < 200) {
            if (i > 0) {
                #pragma unroll
                for (int j = 0; j < 8; ++j) s[j] += (float)qa[j] - (float)qs[j];
            }
            float4* c4 = (float4*)(csum + tid * 8);
            c4[0] = make_float4(s[0], s[1], s[2], s[3]);
            c4[1] = make_float4(s[4], s[5], s[6], s[7]);
            if (i + 1 < P) {   // prefetch slide pair for iteration i+1
                qa = *(const f16x8*)(base + (i + 11) * PSTEP);
                qs = *(const f16x8*)(base + i * PSTEP);
            }
        }
        __syncthreads();                                   // A
        for (int t = tid; t < 5 * ND; t += 256) {
            int pg = t / ND, dxI = t - ND * pg;
            int dx = dxI - (HP - 1), pxb = 6 * pg;
            #pragma unroll
            for (int u = 0; u < 6; ++u) scratch[(pxb + u) * SCW + dxI] = NINF;
            int u0 = max(0, -dx - pxb), u1 = min(5, (HP - 1) - dx - pxb);
            if (u0 <= u1) {
                const float* cp = csum + dx;
                float run = 0.f;
                #pragma unroll
                for (int sr = 0; sr < KS; ++sr) run += cp[(pxb + u0 + sr) * (W_ + 1)];
                int u = u0;
                for (;;) {
                    scratch[(pxb + u) * SCW + dxI] = run * sInv[i * HP + pxb + u + dx];
                    if (++u > u1) break;
                    run += cp[(pxb + u + 10) * (W_ + 1)] - cp[(pxb + u - 1) * (W_ + 1)];
                }
            }
        }
        __syncthreads();                                   // B
        if (tid < 120) {
            int px = tid >> 2, q = tid & 3;
            float m = NINF;
            int d0 = q * 15, d1 = min(d0 + 15, ND);
            for (int d = d0; d < d1; ++d) m = fmaxf(m, scratch[px * SCW + d]);
            partials[tid] = m;
        }
        __syncthreads();                                   // C
        if (tid < HP) {
            float m = fmaxf(fmaxf(partials[tid * 4], partials[tid * 4 + 1]),
                            fmaxf(partials[tid * 4 + 2], partials[tid * 4 + 3]));
            part[(((size_t)b * ND + dyI) * HP + py) * HP + tid] = m;
        }
        // next iteration's sync A orders the shared rewrites
    }
}

// ===========================================================================
// k_C: out[b,py,px] = max over the 30 valid dys: dyI in [29-py, 58-py]
// ===========================================================================
__global__ __launch_bounds__(256)
void k_C(const float* __restrict__ part, float* __restrict__ out) {
    int g = blockIdx.x * 256 + threadIdx.x;
    if (g >= NB * NL) return;
    int b = g / NL, l = g - b * NL, py = l / HP, px = l - py * HP;
    const float* p = part + (((size_t)b * ND + (HP - 1 - py)) * HP + py) * HP + px;
    float m = NINF;
    #pragma unroll
    for (int j = 0; j < HP; ++j) m = fmaxf(m, p[(size_t)j * HP * HP]);
    out[g] = m;
}

extern "C" void kernel_launch(void* const* d_in, const int* in_sizes, int n_in,
                              void* d_out, int out_size, void* d_ws, size_t ws_size,
                              hipStream_t stream) {
    const float* im1 = (const float*)d_in[0];
    const float* im2 = (const float*)d_in[1];
    float* out = (float*)d_out;
    float* invnorm = (float*)((char*)d_ws + 64);               // 14,400 B
    float* part = (float*)((char*)d_ws + 16384);               // 849,600 B
    _Float16* G = (_Float16*)((char*)d_ws + 1048576);          // 20,480,000 B

    k_A<<<680, 256, 0, stream>>>(im1, im2, G, invnorm);
    k_B<<<NBOXJ, 256, 0, stream>>>(G, invnorm, part);
    k_C<<<(NB * NL + 255) / 256, 256, 0, stream>>>(part, out);
}